// Round 5
// baseline (157.193 us; speedup 1.0000x reference)
//
#include <hip/hip_runtime.h>
#include <cstdint>
#include <cmath>

#define B_ 2
#define L_ 1024
#define D_ 256
#define U_ 32

typedef __attribute__((ext_vector_type(8))) short short8;
typedef __attribute__((ext_vector_type(4))) float floatx4;

// ---- workspace layout (bytes); total ~5.8 MB --------------------------------
#define OFF_Q2   0u                       // [2048][32] f32 = 256 KB
#define OFF_K2T  (OFF_Q2 + 262144u)       // [B][U][L] f32 = 256 KB (transposed!)
#define OFF_XT   (OFF_K2T + 262144u)      // [B][D][L] bf16 = 1 MB
#define OFF_A    (OFF_XT + 1048576u)      // [B][L][L] bf16 = 4 MB

__device__ __forceinline__ float bf2f(unsigned short u) {
    union { unsigned int i; float f; } v; v.i = ((unsigned int)u) << 16; return v.f;
}
__device__ __forceinline__ unsigned short f2bf(float f) {
    union { float f; unsigned int i; } v; v.f = f;
    unsigned int r = v.i + 0x7FFFu + ((v.i >> 16) & 1u);
    return (unsigned short)(r >> 16);
}

// Inline dtype sniff (one wave). Little-endian: for fp32 data the EVEN ushorts
// are low mantissa halves (garbage exponents, ~18% plausible); for bf16 data
// they are genuine values. Returns 1 = fp32, 0 = bf16.
__device__ __forceinline__ int sniff_is_f32(const void* x) {
    const unsigned short* xu = (const unsigned short*)x;
    float f = bf2f(xu[2 * (threadIdx.x & 63)]);
    bool plausible = (f == f) && (fabsf(f) < 1e4f) && (fabsf(f) > 1e-10f);
    unsigned long long m = __ballot(plausible);
    return (__popcll(m) >= 60) ? 0 : 1;
}

// ---------------------------------------------------------------------------
// Kernel 1: per row l: q2[row][u] = 2log2e*(x·Wt[:,u]+bh[u]);
//           k2T[b][u][l] = 2log2e*(x·Wx[u,:])   (TRANSPOSED store)
//           xT[b][d][l]  = bf16(x[l][d])
// Wx is staged transposed into LDS (bf16, pad 33) so the k-side inner loop
// reads conflict-free LDS instead of 32-lines-per-instr global loads.
// grid = B*L blocks, 64 threads.
// ---------------------------------------------------------------------------
__global__ void qk_xt_kernel(const void* __restrict__ x,  const void* __restrict__ Wt,
                             const void* __restrict__ Wx, const void* __restrict__ bh,
                             float* __restrict__ q2, float* __restrict__ k2t,
                             unsigned short* __restrict__ xT) {
    const int row = blockIdx.x;              // b*L + l
    const int b = row >> 10, l = row & (L_ - 1);
    const int t = threadIdx.x;               // 0..63
    const int isf32 = sniff_is_f32(x);
    __shared__ __align__(16) float xs[D_];
    __shared__ unsigned short wxp[D_ * 33];  // WxT [d][u] bf16, pad 33

    // stage x row (coalesced)
    float4 f;
    if (isf32) {
        f = ((const float4*)((const float*)x + (size_t)row * D_))[t];
    } else {
        ushort4 v = ((const ushort4*)((const unsigned short*)x + (size_t)row * D_))[t];
        f = make_float4(bf2f(v.x), bf2f(v.y), bf2f(v.z), bf2f(v.w));
    }
    ((float4*)xs)[t] = f;

    // xT transpose write (scattered 2B, 4 instr/block -- small total)
    unsigned short* xtb = xT + (size_t)b * (D_ * L_) + l;
    xtb[(size_t)(4 * t + 0) * L_] = f2bf(f.x);
    xtb[(size_t)(4 * t + 1) * L_] = f2bf(f.y);
    xtb[(size_t)(4 * t + 2) * L_] = f2bf(f.z);
    xtb[(size_t)(4 * t + 3) * L_] = f2bf(f.w);

    // stage WxT into LDS: lane handles d = t + 64c (coalesced global reads;
    // LDS write banks = lane-distinct mod 32 -> <=2-way, free)
    for (int u = 0; u < U_; ++u) {
        #pragma unroll
        for (int c = 0; c < 4; ++c) {
            const int d = t + 64 * c;
            unsigned short wbf;
            if (isf32) wbf = f2bf(((const float*)Wx)[u * D_ + d]);
            else       wbf = ((const unsigned short*)Wx)[u * D_ + d];
            wxp[d * 33 + u] = wbf;
        }
    }
    __syncthreads();

    const float SC = 2.0f * 1.4426950408889634f;   // 2*log2(e): prescale for exp2
    float acc = 0.f;
    if (t < U_) {                                   // q side: Wt [D][U] global, coalesced
        if (isf32) {
            const float* wp = (const float*)Wt + t;
            #pragma unroll 8
            for (int d = 0; d < D_; ++d) acc = fmaf(xs[d], wp[d * U_], acc);
        } else {
            const unsigned short* wp = (const unsigned short*)Wt + t;
            #pragma unroll 8
            for (int d = 0; d < D_; ++d) acc = fmaf(xs[d], bf2f(wp[d * U_]), acc);
        }
        float bhv = isf32 ? ((const float*)bh)[t] : bf2f(((const unsigned short*)bh)[t]);
        q2[(size_t)row * U_ + t] = (acc + bhv) * SC;
    } else {                                        // k side: WxT from LDS, conflict-free
        const int u = t - U_;
        #pragma unroll 8
        for (int d = 0; d < D_; ++d) acc = fmaf(xs[d], bf2f(wxp[d * 33 + u]), acc);
        k2t[(size_t)b * (U_ * L_) + (size_t)u * L_ + l] = acc * SC;
    }
}

// ---------------------------------------------------------------------------
// Kernel 2: one wave per (b, qi).
// alpha_eff[key] = sum_u (-2*Wa[u]) * rcp(exp2(q2[u]+k2T[u][key]) + 1)
// (constants ba and sum_u Wa[u] dropped -- softmax invariant).
// Key->lane mapping: key = jj*256 + 4*lane + c  => k2T float4 loads are 1KB
// fully-coalesced; output stores are packed ushort4 (8B) coalesced.
// Stable softmax via wave-wide shuffle reduce (mapping-agnostic).
// grid = B*L, 64 threads.
// ---------------------------------------------------------------------------
__global__ void alpha_kernel(const float* __restrict__ q2, const float* __restrict__ k2t,
                             const void* __restrict__ Wa, const void* __restrict__ x,
                             unsigned short* __restrict__ a) {
    const int row = blockIdx.x;              // b*L + qi
    const int b = row >> 10;
    const int lane = threadIdx.x;            // 0..63
    const int isf32 = sniff_is_f32(x);

    float qv[U_], wv[U_];
    const float* qrow = q2 + (size_t)row * U_;
    #pragma unroll
    for (int i = 0; i < U_ / 4; ++i) {
        float4 tq = ((const float4*)qrow)[i];
        qv[4*i+0] = tq.x; qv[4*i+1] = tq.y; qv[4*i+2] = tq.z; qv[4*i+3] = tq.w;
    }
    if (isf32) {
        #pragma unroll
        for (int i = 0; i < U_ / 4; ++i) {
            float4 tw = ((const float4*)Wa)[i];
            wv[4*i+0] = -2.f*tw.x; wv[4*i+1] = -2.f*tw.y; wv[4*i+2] = -2.f*tw.z; wv[4*i+3] = -2.f*tw.w;
        }
    } else {
        #pragma unroll
        for (int i = 0; i < U_ / 4; ++i) {
            ushort4 tw = ((const ushort4*)Wa)[i];
            wv[4*i+0] = -2.f*bf2f(tw.x); wv[4*i+1] = -2.f*bf2f(tw.y);
            wv[4*i+2] = -2.f*bf2f(tw.z); wv[4*i+3] = -2.f*bf2f(tw.w);
        }
    }

    const float* kb = k2t + (size_t)b * (U_ * L_);
    float alp[16];
    float amax = -1e30f;
    #pragma unroll
    for (int jj = 0; jj < 4; ++jj) {
        float ac0 = 0.f, ac1 = 0.f, ac2 = 0.f, ac3 = 0.f;
        #pragma unroll 8
        for (int u = 0; u < U_; ++u) {
            float4 kk = *(const float4*)(kb + (size_t)u * L_ + jj * 256 + 4 * lane);
            float e0 = __builtin_amdgcn_exp2f(qv[u] + kk.x);
            float e1 = __builtin_amdgcn_exp2f(qv[u] + kk.y);
            float e2 = __builtin_amdgcn_exp2f(qv[u] + kk.z);
            float e3 = __builtin_amdgcn_exp2f(qv[u] + kk.w);
            ac0 = fmaf(wv[u], __builtin_amdgcn_rcpf(e0 + 1.0f), ac0);
            ac1 = fmaf(wv[u], __builtin_amdgcn_rcpf(e1 + 1.0f), ac1);
            ac2 = fmaf(wv[u], __builtin_amdgcn_rcpf(e2 + 1.0f), ac2);
            ac3 = fmaf(wv[u], __builtin_amdgcn_rcpf(e3 + 1.0f), ac3);
        }
        alp[4*jj+0] = ac0; alp[4*jj+1] = ac1; alp[4*jj+2] = ac2; alp[4*jj+3] = ac3;
        amax = fmaxf(amax, fmaxf(fmaxf(ac0, ac1), fmaxf(ac2, ac3)));
    }
    #pragma unroll
    for (int off = 32; off > 0; off >>= 1) amax = fmaxf(amax, __shfl_xor(amax, off, 64));

    const float L2E = 1.4426950408889634f;
    float s = 0.f;
    #pragma unroll
    for (int j = 0; j < 16; ++j) {
        alp[j] = __builtin_amdgcn_exp2f((alp[j] - amax) * L2E);
        s += alp[j];
    }
    #pragma unroll
    for (int off = 32; off > 0; off >>= 1) s += __shfl_xor(s, off, 64);
    const float rinv = __builtin_amdgcn_rcpf(s);

    unsigned short* ar = a + (size_t)row * L_;
    #pragma unroll
    for (int jj = 0; jj < 4; ++jj) {
        ushort4 pk;
        pk.x = f2bf(alp[4*jj+0] * rinv);
        pk.y = f2bf(alp[4*jj+1] * rinv);
        pk.z = f2bf(alp[4*jj+2] * rinv);
        pk.w = f2bf(alp[4*jj+3] * rinv);
        *(ushort4*)(ar + jj * 256 + 4 * lane) = pk;   // key = jj*256 + 4*lane + c
    }
}

// ---------------------------------------------------------------------------
// Kernel 3: out[b][q][d] = sum_k a[b][q][k] * x[b][k][d], MFMA 16x16x32 bf16.
// One wave = 32(q) x 16(d) tile (2x1 mfma). grid = B*32*16 = 1024 blocks.
// Output dtype matches sniffed input dtype (fp32 expected).
// ---------------------------------------------------------------------------
__global__ void out_gemm_kernel(const unsigned short* __restrict__ a,
                                const unsigned short* __restrict__ xT,
                                const void* __restrict__ x,
                                void* __restrict__ out) {
    const int id = blockIdx.x;
    const int dt = id & 15;          // d-tile of 16
    const int qt = (id >> 4) & 31;   // q-tile of 32
    const int b  = id >> 9;
    const int lane = threadIdx.x;
    const int m  = lane & 15;
    const int ko = (lane >> 4) * 8;
    const int isf32 = sniff_is_f32(x);

    const unsigned short* ab = a  + (size_t)b * (L_ * L_) + (size_t)(qt * 32) * L_;
    const unsigned short* xb = xT + (size_t)b * (D_ * L_) + (size_t)(dt * 16) * L_;

    floatx4 acc0 = {0.f, 0.f, 0.f, 0.f}, acc1 = {0.f, 0.f, 0.f, 0.f};
    #pragma unroll 2
    for (int k0 = 0; k0 < L_; k0 += 32) {
        short8 a0 = *(const short8*)(ab + (size_t)m        * L_ + k0 + ko);
        short8 a1 = *(const short8*)(ab + (size_t)(m + 16) * L_ + k0 + ko);
        short8 b0 = *(const short8*)(xb + (size_t)m        * L_ + k0 + ko);
        acc0 = __builtin_amdgcn_mfma_f32_16x16x32_bf16(a0, b0, acc0, 0, 0, 0);
        acc1 = __builtin_amdgcn_mfma_f32_16x16x32_bf16(a1, b0, acc1, 0, 0, 0);
    }
    // C/D layout (m89-verified): col = lane&15, row = (lane>>4)*4 + reg
    const size_t obase = (size_t)b * (L_ * D_) + (size_t)(qt * 32) * D_ + dt * 16;
    const int col = lane & 15;
    const int rb  = (lane >> 4) * 4;
    if (isf32) {
        float* ob = (float*)out + obase;
        #pragma unroll
        for (int r = 0; r < 4; ++r) {
            ob[(size_t)(rb + r) * D_ + col]      = acc0[r];
            ob[(size_t)(16 + rb + r) * D_ + col] = acc1[r];
        }
    } else {
        unsigned short* ob = (unsigned short*)out + obase;
        #pragma unroll
        for (int r = 0; r < 4; ++r) {
            ob[(size_t)(rb + r) * D_ + col]      = f2bf(acc0[r]);
            ob[(size_t)(16 + rb + r) * D_ + col] = f2bf(acc1[r]);
        }
    }
}

extern "C" void kernel_launch(void* const* d_in, const int* in_sizes, int n_in,
                              void* d_out, int out_size, void* d_ws, size_t ws_size,
                              hipStream_t stream) {
    const void* x  = d_in[0];   // [B,L,D]  dtype sniffed at runtime (fp32 expected)
    const void* Wt = d_in[1];   // [D,U]
    const void* Wx = d_in[2];   // [U,D]
    const void* bh = d_in[3];   // [U]
    const void* Wa = d_in[4];   // [U,1]
    // d_in[5] = ba: constant pre-softmax shift -> mathematically irrelevant.

    char* ws = (char*)d_ws;
    float* q2           = (float*)(ws + OFF_Q2);
    float* k2t          = (float*)(ws + OFF_K2T);
    unsigned short* xT  = (unsigned short*)(ws + OFF_XT);
    unsigned short* a   = (unsigned short*)(ws + OFF_A);

    qk_xt_kernel<<<B_ * L_, 64, 0, stream>>>(x, Wt, Wx, bh, q2, k2t, xT);
    alpha_kernel<<<B_ * L_, 64, 0, stream>>>(q2, k2t, Wa, x, a);
    out_gemm_kernel<<<B_ * 32 * 16, 64, 0, stream>>>(a, xT, x, d_out);
}

// Round 6
// 132.530 us; speedup vs baseline: 1.1861x; 1.1861x over previous
//
#include <hip/hip_runtime.h>
#include <cstdint>
#include <cmath>

#define B_ 2
#define L_ 1024
#define D_ 256
#define U_ 32
#define ROWS_ 2048   // B_*L_

typedef __attribute__((ext_vector_type(8))) short short8;
typedef __attribute__((ext_vector_type(4))) float floatx4;

// ---- workspace layout (bytes); total ~5.6 MB --------------------------------
#define OFF_WB 0u                      // [64][256] bf16 = 32 KB  (rows 0-31: Wt^T, 32-63: Wx)
#define OFF_P  32768u                  // [64][2048] f32 = 512 KB (rows 0-31: q2T = SC*(dot+bh); 32-63: k2T = SC*dot)
#define OFF_XT (OFF_P + 524288u)       // [B][D][L] bf16 = 1 MB
#define OFF_A  (OFF_XT + 1048576u)     // [B][L][L] bf16 = 4 MB

__device__ __forceinline__ float bf2f(unsigned short u) {
    union { unsigned int i; float f; } v; v.i = ((unsigned int)u) << 16; return v.f;
}
__device__ __forceinline__ unsigned short f2bf(float f) {
    union { float f; unsigned int i; } v; v.f = f;
    unsigned int r = v.i + 0x7FFFu + ((v.i >> 16) & 1u);
    return (unsigned short)(r >> 16);
}
// pack two f32 -> two bf16 (round-to-nearest-even) in one uint (b goes high)
__device__ __forceinline__ unsigned int pack_bf(float a, float b) {
    union { float f; unsigned int i; } ua, ub; ua.f = a; ub.f = b;
    unsigned int ra = ua.i + 0x7FFFu + ((ua.i >> 16) & 1u);
    unsigned int rb = ub.i + 0x7FFFu + ((ub.i >> 16) & 1u);
    return (ra >> 16) | (rb & 0xFFFF0000u);
}

// Inline dtype sniff (one wave). Little-endian: for fp32 data the EVEN ushorts
// are low mantissa halves (garbage exponents, ~18% plausible); for bf16 data
// they are genuine values. Returns 1 = fp32, 0 = bf16.
__device__ __forceinline__ int sniff_is_f32(const void* x) {
    const unsigned short* xu = (const unsigned short*)x;
    float f = bf2f(xu[2 * (threadIdx.x & 63)]);
    bool plausible = (f == f) && (fabsf(f) < 1e4f) && (fabsf(f) > 1e-10f);
    unsigned long long m = __ballot(plausible);
    return (__popcll(m) >= 60) ? 0 : 1;
}

// ---------------------------------------------------------------------------
// prep_w: build Wb[64][256] bf16 (A-operand layout: unit-major, d-contiguous).
//   u<32 : Wb[u][d] = Wt[d][u]  (transpose via LDS tile, pad 33)   -- block 0
//   u>=32: Wb[u][d] = Wx[u-32][d] (direct coalesced copy)          -- blocks 1-8
// grid = 9 blocks x 256 threads. Total data 64 KB -> ~2 us.
// ---------------------------------------------------------------------------
__global__ void prep_w(const void* __restrict__ Wt, const void* __restrict__ Wx,
                       const void* __restrict__ x, unsigned short* __restrict__ Wb) {
    const int t = threadIdx.x;
    const int isf32 = sniff_is_f32(x);
    __shared__ float wl[D_ * 33];   // 33.8 KB

    if (blockIdx.x == 0) {
        // load Wt [D][U] coalesced -> LDS padded [d][u]
        for (int j = 0; j < 32; ++j) {
            const int i = t + 256 * j;            // i = d*32 + u
            float v = isf32 ? ((const float*)Wt)[i] : bf2f(((const unsigned short*)Wt)[i]);
            wl[(i >> 5) * 33 + (i & 31)] = v;
        }
        __syncthreads();
        // write Wb[u][d] for u<32, two d per thread-iter (uint store)
        for (int j = 0; j < 16; ++j) {
            const int o = 2 * (t + 256 * j);      // o = u*256 + d (d even)
            const int u = o >> 8, d = o & 255;
            unsigned int p = pack_bf(wl[d * 33 + u], wl[(d + 1) * 33 + u]);
            *(unsigned int*)(Wb + (size_t)u * D_ + d) = p;
        }
    } else {
        // Wx: 8192 elements = 4096 pairs; blocks 1-8 -> 512 pairs each
        #pragma unroll
        for (int j = 0; j < 2; ++j) {
            const int pidx = (blockIdx.x - 1) * 512 + j * 256 + t;
            const int e = 2 * pidx;               // flat index into Wx == into Wb[32..]
            unsigned int p;
            if (isf32) {
                p = pack_bf(((const float*)Wx)[e], ((const float*)Wx)[e + 1]);
            } else {
                const unsigned short* wxu = (const unsigned short*)Wx;
                p = (unsigned int)wxu[e] | ((unsigned int)wxu[e + 1] << 16);
            }
            *(unsigned int*)(Wb + 8192 + e) = p;
        }
    }
}

// ---------------------------------------------------------------------------
// xt_kernel: xT[b][d][l] = bf16(x[b][l][d]). grid = 2048 x 64.
// Coalesced row read, 4 scattered 2B stores per thread (~0.5M sector-touches
// total, ~3-5 us).
// ---------------------------------------------------------------------------
__global__ void xt_kernel(const void* __restrict__ x, unsigned short* __restrict__ xT) {
    const int row = blockIdx.x;              // b*L + l
    const int b = row >> 10, l = row & (L_ - 1);
    const int t = threadIdx.x;
    const int isf32 = sniff_is_f32(x);
    float4 f;
    if (isf32) {
        f = ((const float4*)((const float*)x + (size_t)row * D_))[t];
    } else {
        ushort4 v = ((const ushort4*)((const unsigned short*)x + (size_t)row * D_))[t];
        f = make_float4(bf2f(v.x), bf2f(v.y), bf2f(v.z), bf2f(v.w));
    }
    unsigned short* xtb = xT + (size_t)b * (D_ * L_) + l;
    xtb[(size_t)(4 * t + 0) * L_] = f2bf(f.x);
    xtb[(size_t)(4 * t + 1) * L_] = f2bf(f.y);
    xtb[(size_t)(4 * t + 2) * L_] = f2bf(f.z);
    xtb[(size_t)(4 * t + 3) * L_] = f2bf(f.w);
}

// convert 8 consecutive f32 -> short8 bf16 (RNE)
__device__ __forceinline__ short8 cvt8(const float* p) {
    float4 fa = *(const float4*)p;
    float4 fb = *(const float4*)(p + 4);
    union { short8 s; unsigned int u[4]; } r;
    r.u[0] = pack_bf(fa.x, fa.y);
    r.u[1] = pack_bf(fa.z, fa.w);
    r.u[2] = pack_bf(fb.x, fb.y);
    r.u[3] = pack_bf(fb.z, fb.w);
    return r.s;
}

// ---------------------------------------------------------------------------
// proj_q: P[64][2048] = SC*(Wb @ x^T [+ bh for u<32]) via MFMA 16x16x32 bf16.
// One wave = 32(u) x 32(row) tile; grid = 64 n-tiles x 2 m-tiles = 128 blocks.
// A-frag: Wb[u][d] d-contiguous -> 16B loads. B-frag: x[row][d] d-contiguous
// -> 2x16B f32 loads + pack (or direct short8 when input is bf16).
// P rows 0-31 = q2T (bias applied), rows 32-63 = k2T. Stores coalesced f32.
// ---------------------------------------------------------------------------
__global__ void proj_q(const void* __restrict__ x, const unsigned short* __restrict__ Wb,
                       const void* __restrict__ bh, float* __restrict__ P) {
    const int nt = blockIdx.x >> 1;      // row tile (32 rows)
    const int mt = blockIdx.x & 1;       // 0: units 0-31 (q), 1: units 32-63 (k)
    const int lane = threadIdx.x;
    const int m = lane & 15;
    const int ko8 = (lane >> 4) * 8;
    const int isf32 = sniff_is_f32(x);
    const int n0 = nt * 32;
    const int u0 = mt * 32;

    const unsigned short* a0p = Wb + (size_t)(u0 + m) * D_;
    const unsigned short* a1p = Wb + (size_t)(u0 + 16 + m) * D_;

    floatx4 acc00 = {0,0,0,0}, acc01 = {0,0,0,0}, acc10 = {0,0,0,0}, acc11 = {0,0,0,0};
    #pragma unroll
    for (int k0 = 0; k0 < D_; k0 += 32) {
        const int ks = k0 + ko8;
        short8 a0 = *(const short8*)(a0p + ks);
        short8 a1 = *(const short8*)(a1p + ks);
        short8 b0, b1;
        if (isf32) {
            b0 = cvt8((const float*)x + (size_t)(n0 + m) * D_ + ks);
            b1 = cvt8((const float*)x + (size_t)(n0 + 16 + m) * D_ + ks);
        } else {
            b0 = *(const short8*)((const unsigned short*)x + (size_t)(n0 + m) * D_ + ks);
            b1 = *(const short8*)((const unsigned short*)x + (size_t)(n0 + 16 + m) * D_ + ks);
        }
        acc00 = __builtin_amdgcn_mfma_f32_16x16x32_bf16(a0, b0, acc00, 0, 0, 0);
        acc01 = __builtin_amdgcn_mfma_f32_16x16x32_bf16(a0, b1, acc01, 0, 0, 0);
        acc10 = __builtin_amdgcn_mfma_f32_16x16x32_bf16(a1, b0, acc10, 0, 0, 0);
        acc11 = __builtin_amdgcn_mfma_f32_16x16x32_bf16(a1, b1, acc11, 0, 0, 0);
    }
    // C/D layout: col(n=row)=lane&15, row(m=u)=(lane>>4)*4+reg
    const float SC = 2.0f * 1.4426950408889634f;   // 2*log2(e)
    const int col = lane & 15;
    const int rb  = (lane >> 4) * 4;
    #pragma unroll
    for (int r = 0; r < 4; ++r) {
        const int ul0 = rb + r, ul1 = rb + r + 16;
        float bh0 = 0.f, bh1 = 0.f;
        if (mt == 0) {   // q-side: add bias (bias depends on u only)
            bh0 = isf32 ? ((const float*)bh)[ul0] : bf2f(((const unsigned short*)bh)[ul0]);
            bh1 = isf32 ? ((const float*)bh)[ul1] : bf2f(((const unsigned short*)bh)[ul1]);
        }
        P[(size_t)(u0 + ul0) * ROWS_ + n0 + col]      = SC * (acc00[r] + bh0);
        P[(size_t)(u0 + ul0) * ROWS_ + n0 + 16 + col] = SC * (acc01[r] + bh0);
        P[(size_t)(u0 + ul1) * ROWS_ + n0 + col]      = SC * (acc10[r] + bh1);
        P[(size_t)(u0 + ul1) * ROWS_ + n0 + 16 + col] = SC * (acc11[r] + bh1);
    }
}

// ---------------------------------------------------------------------------
// alpha_kernel: one wave per (b, qi).
// alpha_eff[key] = sum_u (-2*Wa[u]) * rcp(exp2(q2T[u][row] + k2T[u][key]) + 1)
// (constants ba and sum_u Wa[u] dropped -- softmax invariant).
// q via 32 uniform broadcast loads; k2T float4 loads 1KB-coalesced.
// key = jj*256 + 4*lane + c; stores packed ushort4. grid = 2048 x 64.
// ---------------------------------------------------------------------------
__global__ void alpha_kernel(const float* __restrict__ P, const void* __restrict__ Wa,
                             const void* __restrict__ x, unsigned short* __restrict__ a) {
    const int row = blockIdx.x;              // global row = b*L + qi
    const int b = row >> 10;
    const int lane = threadIdx.x;
    const int isf32 = sniff_is_f32(x);

    float qv[U_], wv[U_];
    #pragma unroll
    for (int u = 0; u < U_; ++u) qv[u] = P[(size_t)u * ROWS_ + row];   // uniform loads
    if (isf32) {
        #pragma unroll
        for (int i = 0; i < U_ / 4; ++i) {
            float4 tw = ((const float4*)Wa)[i];
            wv[4*i+0] = -2.f*tw.x; wv[4*i+1] = -2.f*tw.y; wv[4*i+2] = -2.f*tw.z; wv[4*i+3] = -2.f*tw.w;
        }
    } else {
        #pragma unroll
        for (int i = 0; i < U_ / 4; ++i) {
            ushort4 tw = ((const ushort4*)Wa)[i];
            wv[4*i+0] = -2.f*bf2f(tw.x); wv[4*i+1] = -2.f*bf2f(tw.y);
            wv[4*i+2] = -2.f*bf2f(tw.z); wv[4*i+3] = -2.f*bf2f(tw.w);
        }
    }

    const float* kb = P + (size_t)32 * ROWS_ + (size_t)b * L_;   // k2T[u][key]: stride ROWS_ per u
    float alp[16];
    float amax = -1e30f;
    #pragma unroll
    for (int jj = 0; jj < 4; ++jj) {
        float ac0 = 0.f, ac1 = 0.f, ac2 = 0.f, ac3 = 0.f;
        #pragma unroll 8
        for (int u = 0; u < U_; ++u) {
            float4 kk = *(const float4*)(kb + (size_t)u * ROWS_ + jj * 256 + 4 * lane);
            float e0 = __builtin_amdgcn_exp2f(qv[u] + kk.x);
            float e1 = __builtin_amdgcn_exp2f(qv[u] + kk.y);
            float e2 = __builtin_amdgcn_exp2f(qv[u] + kk.z);
            float e3 = __builtin_amdgcn_exp2f(qv[u] + kk.w);
            ac0 = fmaf(wv[u], __builtin_amdgcn_rcpf(e0 + 1.0f), ac0);
            ac1 = fmaf(wv[u], __builtin_amdgcn_rcpf(e1 + 1.0f), ac1);
            ac2 = fmaf(wv[u], __builtin_amdgcn_rcpf(e2 + 1.0f), ac2);
            ac3 = fmaf(wv[u], __builtin_amdgcn_rcpf(e3 + 1.0f), ac3);
        }
        alp[4*jj+0] = ac0; alp[4*jj+1] = ac1; alp[4*jj+2] = ac2; alp[4*jj+3] = ac3;
        amax = fmaxf(amax, fmaxf(fmaxf(ac0, ac1), fmaxf(ac2, ac3)));
    }
    #pragma unroll
    for (int off = 32; off > 0; off >>= 1) amax = fmaxf(amax, __shfl_xor(amax, off, 64));

    const float L2E = 1.4426950408889634f;
    float s = 0.f;
    #pragma unroll
    for (int j = 0; j < 16; ++j) {
        alp[j] = __builtin_amdgcn_exp2f((alp[j] - amax) * L2E);
        s += alp[j];
    }
    #pragma unroll
    for (int off = 32; off > 0; off >>= 1) s += __shfl_xor(s, off, 64);
    const float rinv = __builtin_amdgcn_rcpf(s);

    unsigned short* ar = a + (size_t)row * L_;
    #pragma unroll
    for (int jj = 0; jj < 4; ++jj) {
        ushort4 pk;
        pk.x = f2bf(alp[4*jj+0] * rinv);
        pk.y = f2bf(alp[4*jj+1] * rinv);
        pk.z = f2bf(alp[4*jj+2] * rinv);
        pk.w = f2bf(alp[4*jj+3] * rinv);
        *(ushort4*)(ar + jj * 256 + 4 * lane) = pk;
    }
}

// ---------------------------------------------------------------------------
// out_gemm_kernel: out[b][q][d] = sum_k a[b][q][k] * x[b][k][d], MFMA.
// One wave = 32(q) x 16(d); grid = B*32*16 = 1024 blocks.
// ---------------------------------------------------------------------------
__global__ void out_gemm_kernel(const unsigned short* __restrict__ a,
                                const unsigned short* __restrict__ xT,
                                const void* __restrict__ x,
                                void* __restrict__ out) {
    const int id = blockIdx.x;
    const int dt = id & 15;
    const int qt = (id >> 4) & 31;
    const int b  = id >> 9;
    const int lane = threadIdx.x;
    const int m  = lane & 15;
    const int ko = (lane >> 4) * 8;
    const int isf32 = sniff_is_f32(x);

    const unsigned short* ab = a  + (size_t)b * (L_ * L_) + (size_t)(qt * 32) * L_;
    const unsigned short* xb = xT + (size_t)b * (D_ * L_) + (size_t)(dt * 16) * L_;

    floatx4 acc0 = {0,0,0,0}, acc1 = {0,0,0,0};
    #pragma unroll 2
    for (int k0 = 0; k0 < L_; k0 += 32) {
        short8 a0 = *(const short8*)(ab + (size_t)m        * L_ + k0 + ko);
        short8 a1 = *(const short8*)(ab + (size_t)(m + 16) * L_ + k0 + ko);
        short8 b0 = *(const short8*)(xb + (size_t)m        * L_ + k0 + ko);
        acc0 = __builtin_amdgcn_mfma_f32_16x16x32_bf16(a0, b0, acc0, 0, 0, 0);
        acc1 = __builtin_amdgcn_mfma_f32_16x16x32_bf16(a1, b0, acc1, 0, 0, 0);
    }
    const size_t obase = (size_t)b * (L_ * D_) + (size_t)(qt * 32) * D_ + dt * 16;
    const int col = lane & 15;
    const int rb  = (lane >> 4) * 4;
    if (isf32) {
        float* ob = (float*)out + obase;
        #pragma unroll
        for (int r = 0; r < 4; ++r) {
            ob[(size_t)(rb + r) * D_ + col]      = acc0[r];
            ob[(size_t)(16 + rb + r) * D_ + col] = acc1[r];
        }
    } else {
        unsigned short* ob = (unsigned short*)out + obase;
        #pragma unroll
        for (int r = 0; r < 4; ++r) {
            ob[(size_t)(rb + r) * D_ + col]      = f2bf(acc0[r]);
            ob[(size_t)(16 + rb + r) * D_ + col] = f2bf(acc1[r]);
        }
    }
}

extern "C" void kernel_launch(void* const* d_in, const int* in_sizes, int n_in,
                              void* d_out, int out_size, void* d_ws, size_t ws_size,
                              hipStream_t stream) {
    const void* x  = d_in[0];   // [B,L,D]  dtype sniffed at runtime (fp32 expected)
    const void* Wt = d_in[1];   // [D,U]
    const void* Wx = d_in[2];   // [U,D]
    const void* bh = d_in[3];   // [U]
    const void* Wa = d_in[4];   // [U,1]
    // d_in[5] = ba: constant pre-softmax shift -> mathematically irrelevant.

    char* ws = (char*)d_ws;
    unsigned short* Wb  = (unsigned short*)(ws + OFF_WB);
    float*          P   = (float*)(ws + OFF_P);
    unsigned short* xT  = (unsigned short*)(ws + OFF_XT);
    unsigned short* a   = (unsigned short*)(ws + OFF_A);

    prep_w<<<9, 256, 0, stream>>>(Wt, Wx, x, Wb);
    xt_kernel<<<ROWS_, 64, 0, stream>>>(x, xT);
    proj_q<<<128, 64, 0, stream>>>(x, Wb, bh, P);
    alpha_kernel<<<ROWS_, 64, 0, stream>>>(P, Wa, x, a);
    out_gemm_kernel<<<B_ * 32 * 16, 64, 0, stream>>>(a, xT, x, d_out);
}

// Round 7
// 126.478 us; speedup vs baseline: 1.2428x; 1.0479x over previous
//
#include <hip/hip_runtime.h>
#include <cstdint>
#include <cmath>

#define B_ 2
#define L_ 1024
#define D_ 256
#define U_ 32
#define ROWS_ 2048   // B_*L_

typedef __attribute__((ext_vector_type(8))) short short8;
typedef __attribute__((ext_vector_type(4))) float floatx4;

// ---- workspace layout (bytes); total ~5.6 MB --------------------------------
#define OFF_WB 0u                      // [64][256] bf16 = 32 KB  (rows 0-31: Wt^T, 32-63: Wx)
#define OFF_P  32768u                  // [64][2048] f32 = 512 KB (rows 0-31: q2T = SC*(dot+bh); 32-63: k2T = SC*dot)
#define OFF_XT (OFF_P + 524288u)       // [B][D][L] bf16 = 1 MB
#define OFF_A  (OFF_XT + 1048576u)     // [B][L][L] bf16 = 4 MB

__device__ __forceinline__ float bf2f(unsigned short u) {
    union { unsigned int i; float f; } v; v.i = ((unsigned int)u) << 16; return v.f;
}
__device__ __forceinline__ unsigned short f2bf(float f) {
    union { float f; unsigned int i; } v; v.f = f;
    unsigned int r = v.i + 0x7FFFu + ((v.i >> 16) & 1u);
    return (unsigned short)(r >> 16);
}
// pack two f32 -> two bf16 (RNE) in one uint (b goes high)
__device__ __forceinline__ unsigned int pack_bf(float a, float b) {
    union { float f; unsigned int i; } ua, ub; ua.f = a; ub.f = b;
    unsigned int ra = ua.i + 0x7FFFu + ((ua.i >> 16) & 1u);
    unsigned int rb = ub.i + 0x7FFFu + ((ub.i >> 16) & 1u);
    return (ra >> 16) | (rb & 0xFFFF0000u);
}

// Inline dtype sniff (per wave). Little-endian: for fp32 data the EVEN ushorts
// are low mantissa halves (garbage exponents, ~18% plausible); for bf16 data
// they are genuine values. Returns 1 = fp32, 0 = bf16.
__device__ __forceinline__ int sniff_is_f32(const void* x) {
    const unsigned short* xu = (const unsigned short*)x;
    float f = bf2f(xu[2 * (threadIdx.x & 63)]);
    bool plausible = (f == f) && (fabsf(f) < 1e4f) && (fabsf(f) > 1e-10f);
    unsigned long long m = __ballot(plausible);
    return (__popcll(m) >= 60) ? 0 : 1;
}

// ---------------------------------------------------------------------------
// K1 prep_xt: blocks 0-8 build Wb[64][256] bf16 (A-operand layout);
//             blocks 9.. write xT[b][d][l] = bf16(x[b][l][d]), 4 rows/block
//             (wave w of 4 handles row 4*(blk-9)+w; coalesced row read,
//              4 scattered 2B stores/thread).
// grid = 9 + 512 blocks x 256 threads.
// ---------------------------------------------------------------------------
__global__ void prep_xt(const void* __restrict__ Wt, const void* __restrict__ Wx,
                        const void* __restrict__ x, unsigned short* __restrict__ Wb,
                        unsigned short* __restrict__ xT) {
    const int t = threadIdx.x;
    const int isf32 = sniff_is_f32(x);

    if (blockIdx.x == 0) {
        __shared__ float wl[D_ * 33];   // 33.8 KB
        // load Wt [D][U] coalesced -> LDS padded [d][u]
        for (int j = 0; j < 32; ++j) {
            const int i = t + 256 * j;            // i = d*32 + u
            float v = isf32 ? ((const float*)Wt)[i] : bf2f(((const unsigned short*)Wt)[i]);
            wl[(i >> 5) * 33 + (i & 31)] = v;
        }
        __syncthreads();
        // write Wb[u][d] for u<32, two d per thread-iter (uint store)
        for (int j = 0; j < 16; ++j) {
            const int o = 2 * (t + 256 * j);      // o = u*256 + d (d even)
            const int u = o >> 8, d = o & 255;
            unsigned int p = pack_bf(wl[d * 33 + u], wl[(d + 1) * 33 + u]);
            *(unsigned int*)(Wb + (size_t)u * D_ + d) = p;
        }
    } else if (blockIdx.x < 9) {
        // Wx: 8192 elements = 4096 pairs; blocks 1-8 -> 512 pairs each
        #pragma unroll
        for (int j = 0; j < 2; ++j) {
            const int pidx = (blockIdx.x - 1) * 512 + j * 256 + t;
            const int e = 2 * pidx;               // flat index into Wx == into Wb[32..]
            unsigned int p;
            if (isf32) {
                p = pack_bf(((const float*)Wx)[e], ((const float*)Wx)[e + 1]);
            } else {
                const unsigned short* wxu = (const unsigned short*)Wx;
                p = (unsigned int)wxu[e] | ((unsigned int)wxu[e + 1] << 16);
            }
            *(unsigned int*)(Wb + 8192 + e) = p;
        }
    } else {
        const int row = (blockIdx.x - 9) * 4 + (t >> 6);   // b*L + l
        const int b = row >> 10, l = row & (L_ - 1);
        const int lane = t & 63;
        float4 f;
        if (isf32) {
            f = ((const float4*)((const float*)x + (size_t)row * D_))[lane];
        } else {
            ushort4 v = ((const ushort4*)((const unsigned short*)x + (size_t)row * D_))[lane];
            f = make_float4(bf2f(v.x), bf2f(v.y), bf2f(v.z), bf2f(v.w));
        }
        unsigned short* xtb = xT + (size_t)b * (D_ * L_) + l;
        xtb[(size_t)(4 * lane + 0) * L_] = f2bf(f.x);
        xtb[(size_t)(4 * lane + 1) * L_] = f2bf(f.y);
        xtb[(size_t)(4 * lane + 2) * L_] = f2bf(f.z);
        xtb[(size_t)(4 * lane + 3) * L_] = f2bf(f.w);
    }
}

// convert 8 consecutive f32 -> short8 bf16 (RNE)
__device__ __forceinline__ short8 cvt8(const float* p) {
    float4 fa = *(const float4*)p;
    float4 fb = *(const float4*)(p + 4);
    union { short8 s; unsigned int u[4]; } r;
    r.u[0] = pack_bf(fa.x, fa.y);
    r.u[1] = pack_bf(fa.z, fa.w);
    r.u[2] = pack_bf(fb.x, fb.y);
    r.u[3] = pack_bf(fb.z, fb.w);
    return r.s;
}

// ---------------------------------------------------------------------------
// K2 proj_q: P[64][2048] = SC*(Wb @ x^T [+ bh for u<32]) via MFMA 16x16x32 bf16.
// One wave = 32(u) x 32(row); grid = 64 n-tiles x 2 m-tiles = 128 blocks x 64.
// P rows 0-31 = q2T (bias applied), rows 32-63 = k2T. Coalesced f32 stores.
// ---------------------------------------------------------------------------
__global__ void proj_q(const void* __restrict__ x, const unsigned short* __restrict__ Wb,
                       const void* __restrict__ bh, float* __restrict__ P) {
    const int nt = blockIdx.x >> 1;
    const int mt = blockIdx.x & 1;       // 0: units 0-31 (q), 1: units 32-63 (k)
    const int lane = threadIdx.x;
    const int m = lane & 15;
    const int ko8 = (lane >> 4) * 8;
    const int isf32 = sniff_is_f32(x);
    const int n0 = nt * 32;
    const int u0 = mt * 32;

    const unsigned short* a0p = Wb + (size_t)(u0 + m) * D_;
    const unsigned short* a1p = Wb + (size_t)(u0 + 16 + m) * D_;

    floatx4 acc00 = {0,0,0,0}, acc01 = {0,0,0,0}, acc10 = {0,0,0,0}, acc11 = {0,0,0,0};
    #pragma unroll
    for (int k0 = 0; k0 < D_; k0 += 32) {
        const int ks = k0 + ko8;
        short8 a0 = *(const short8*)(a0p + ks);
        short8 a1 = *(const short8*)(a1p + ks);
        short8 b0, b1;
        if (isf32) {
            b0 = cvt8((const float*)x + (size_t)(n0 + m) * D_ + ks);
            b1 = cvt8((const float*)x + (size_t)(n0 + 16 + m) * D_ + ks);
        } else {
            b0 = *(const short8*)((const unsigned short*)x + (size_t)(n0 + m) * D_ + ks);
            b1 = *(const short8*)((const unsigned short*)x + (size_t)(n0 + 16 + m) * D_ + ks);
        }
        acc00 = __builtin_amdgcn_mfma_f32_16x16x32_bf16(a0, b0, acc00, 0, 0, 0);
        acc01 = __builtin_amdgcn_mfma_f32_16x16x32_bf16(a0, b1, acc01, 0, 0, 0);
        acc10 = __builtin_amdgcn_mfma_f32_16x16x32_bf16(a1, b0, acc10, 0, 0, 0);
        acc11 = __builtin_amdgcn_mfma_f32_16x16x32_bf16(a1, b1, acc11, 0, 0, 0);
    }
    // C/D layout: col(n=row)=lane&15, row(m=u)=(lane>>4)*4+reg
    const float SC = 2.0f * 1.4426950408889634f;   // 2*log2(e)
    const int col = lane & 15;
    const int rb  = (lane >> 4) * 4;
    #pragma unroll
    for (int r = 0; r < 4; ++r) {
        const int ul0 = rb + r, ul1 = rb + r + 16;
        float bh0 = 0.f, bh1 = 0.f;
        if (mt == 0) {
            bh0 = isf32 ? ((const float*)bh)[ul0] : bf2f(((const unsigned short*)bh)[ul0]);
            bh1 = isf32 ? ((const float*)bh)[ul1] : bf2f(((const unsigned short*)bh)[ul1]);
        }
        P[(size_t)(u0 + ul0) * ROWS_ + n0 + col]      = SC * (acc00[r] + bh0);
        P[(size_t)(u0 + ul0) * ROWS_ + n0 + 16 + col] = SC * (acc01[r] + bh0);
        P[(size_t)(u0 + ul1) * ROWS_ + n0 + col]      = SC * (acc10[r] + bh1);
        P[(size_t)(u0 + ul1) * ROWS_ + n0 + 16 + col] = SC * (acc11[r] + bh1);
    }
}

// ---------------------------------------------------------------------------
// K3 alpha_kernel: 4 q-rows per 256-thread block (wave w -> row 4*blk+w);
// the 4 waves share the 128 KB k2T working set through L1 (cuts L2 traffic 4x).
// alpha_eff[key] = sum_u (-2*Wa[u]) * rcp(exp2(q2T[u][row] + k2T[u][key]) + 1)
// (constants ba and sum_u Wa[u] dropped -- softmax invariant). Stable softmax,
// bf16 weights out, coalesced. grid = 512 x 256.
// ---------------------------------------------------------------------------
__global__ void alpha_kernel(const float* __restrict__ P, const void* __restrict__ Wa,
                             const void* __restrict__ x, unsigned short* __restrict__ a) {
    const int row = blockIdx.x * 4 + (threadIdx.x >> 6);   // b*L + qi
    const int b = row >> 10;
    const int lane = threadIdx.x & 63;
    const int isf32 = sniff_is_f32(x);

    float qv[U_], wv[U_];
    #pragma unroll
    for (int u = 0; u < U_; ++u) qv[u] = P[(size_t)u * ROWS_ + row];   // uniform loads
    if (isf32) {
        #pragma unroll
        for (int i = 0; i < U_ / 4; ++i) {
            float4 tw = ((const float4*)Wa)[i];
            wv[4*i+0] = -2.f*tw.x; wv[4*i+1] = -2.f*tw.y; wv[4*i+2] = -2.f*tw.z; wv[4*i+3] = -2.f*tw.w;
        }
    } else {
        #pragma unroll
        for (int i = 0; i < U_ / 4; ++i) {
            ushort4 tw = ((const ushort4*)Wa)[i];
            wv[4*i+0] = -2.f*bf2f(tw.x); wv[4*i+1] = -2.f*bf2f(tw.y);
            wv[4*i+2] = -2.f*bf2f(tw.z); wv[4*i+3] = -2.f*bf2f(tw.w);
        }
    }

    const float* kb = P + (size_t)32 * ROWS_ + (size_t)b * L_;   // k2T[u][key], stride ROWS_
    float alp[16];
    float amax = -1e30f;
    #pragma unroll
    for (int jj = 0; jj < 4; ++jj) {
        float ac0 = 0.f, ac1 = 0.f, ac2 = 0.f, ac3 = 0.f;
        #pragma unroll 8
        for (int u = 0; u < U_; ++u) {
            float4 kk = *(const float4*)(kb + (size_t)u * ROWS_ + jj * 256 + 4 * lane);
            float e0 = __builtin_amdgcn_exp2f(qv[u] + kk.x);
            float e1 = __builtin_amdgcn_exp2f(qv[u] + kk.y);
            float e2 = __builtin_amdgcn_exp2f(qv[u] + kk.z);
            float e3 = __builtin_amdgcn_exp2f(qv[u] + kk.w);
            ac0 = fmaf(wv[u], __builtin_amdgcn_rcpf(e0 + 1.0f), ac0);
            ac1 = fmaf(wv[u], __builtin_amdgcn_rcpf(e1 + 1.0f), ac1);
            ac2 = fmaf(wv[u], __builtin_amdgcn_rcpf(e2 + 1.0f), ac2);
            ac3 = fmaf(wv[u], __builtin_amdgcn_rcpf(e3 + 1.0f), ac3);
        }
        alp[4*jj+0] = ac0; alp[4*jj+1] = ac1; alp[4*jj+2] = ac2; alp[4*jj+3] = ac3;
        amax = fmaxf(amax, fmaxf(fmaxf(ac0, ac1), fmaxf(ac2, ac3)));
    }
    #pragma unroll
    for (int off = 32; off > 0; off >>= 1) amax = fmaxf(amax, __shfl_xor(amax, off, 64));

    const float L2E = 1.4426950408889634f;
    float s = 0.f;
    #pragma unroll
    for (int j = 0; j < 16; ++j) {
        alp[j] = __builtin_amdgcn_exp2f((alp[j] - amax) * L2E);
        s += alp[j];
    }
    #pragma unroll
    for (int off = 32; off > 0; off >>= 1) s += __shfl_xor(s, off, 64);
    const float rinv = __builtin_amdgcn_rcpf(s);

    unsigned short* ar = a + (size_t)row * L_;
    #pragma unroll
    for (int jj = 0; jj < 4; ++jj) {
        ushort4 pk;
        pk.x = f2bf(alp[4*jj+0] * rinv);
        pk.y = f2bf(alp[4*jj+1] * rinv);
        pk.z = f2bf(alp[4*jj+2] * rinv);
        pk.w = f2bf(alp[4*jj+3] * rinv);
        *(ushort4*)(ar + jj * 256 + 4 * lane) = pk;
    }
}

// ---------------------------------------------------------------------------
// K4 out_gemm: out[b][q][d] = sum_k a[b][q][k] * x[b][k][d], MFMA 16x16x32.
// One wave = 32(q) x 16(d); grid = B*32*16 = 1024 blocks x 64.
// Software-pipelined K-loop: next iteration's frags loaded before current MFMAs.
// ---------------------------------------------------------------------------
__global__ void out_gemm_kernel(const unsigned short* __restrict__ a,
                                const unsigned short* __restrict__ xT,
                                const void* __restrict__ x,
                                void* __restrict__ out) {
    const int id = blockIdx.x;
    const int dt = id & 15;
    const int qt = (id >> 4) & 31;
    const int b  = id >> 9;
    const int lane = threadIdx.x;
    const int m  = lane & 15;
    const int ko = (lane >> 4) * 8;
    const int isf32 = sniff_is_f32(x);

    const unsigned short* ap0 = a  + (size_t)b * (L_ * L_) + (size_t)(qt * 32 + m) * L_ + ko;
    const unsigned short* ap1 = ap0 + (size_t)16 * L_;
    const unsigned short* bp0 = xT + (size_t)b * (D_ * L_) + (size_t)(dt * 16 + m) * L_ + ko;

    floatx4 acc0 = {0,0,0,0}, acc1 = {0,0,0,0};
    short8 a0 = *(const short8*)(ap0);
    short8 a1 = *(const short8*)(ap1);
    short8 b0 = *(const short8*)(bp0);
    for (int k0 = 32; k0 < L_; k0 += 32) {
        short8 na0 = *(const short8*)(ap0 + k0);
        short8 na1 = *(const short8*)(ap1 + k0);
        short8 nb0 = *(const short8*)(bp0 + k0);
        acc0 = __builtin_amdgcn_mfma_f32_16x16x32_bf16(a0, b0, acc0, 0, 0, 0);
        acc1 = __builtin_amdgcn_mfma_f32_16x16x32_bf16(a1, b0, acc1, 0, 0, 0);
        a0 = na0; a1 = na1; b0 = nb0;
    }
    acc0 = __builtin_amdgcn_mfma_f32_16x16x32_bf16(a0, b0, acc0, 0, 0, 0);
    acc1 = __builtin_amdgcn_mfma_f32_16x16x32_bf16(a1, b0, acc1, 0, 0, 0);

    // C/D layout (m89-verified): col = lane&15, row = (lane>>4)*4 + reg
    const size_t obase = (size_t)b * (L_ * D_) + (size_t)(qt * 32) * D_ + dt * 16;
    const int col = lane & 15;
    const int rb  = (lane >> 4) * 4;
    if (isf32) {
        float* ob = (float*)out + obase;
        #pragma unroll
        for (int r = 0; r < 4; ++r) {
            ob[(size_t)(rb + r) * D_ + col]      = acc0[r];
            ob[(size_t)(16 + rb + r) * D_ + col] = acc1[r];
        }
    } else {
        unsigned short* ob = (unsigned short*)out + obase;
        #pragma unroll
        for (int r = 0; r < 4; ++r) {
            ob[(size_t)(rb + r) * D_ + col]      = f2bf(acc0[r]);
            ob[(size_t)(16 + rb + r) * D_ + col] = f2bf(acc1[r]);
        }
    }
}

extern "C" void kernel_launch(void* const* d_in, const int* in_sizes, int n_in,
                              void* d_out, int out_size, void* d_ws, size_t ws_size,
                              hipStream_t stream) {
    const void* x  = d_in[0];   // [B,L,D]  dtype sniffed at runtime (fp32 expected)
    const void* Wt = d_in[1];   // [D,U]
    const void* Wx = d_in[2];   // [U,D]
    const void* bh = d_in[3];   // [U]
    const void* Wa = d_in[4];   // [U,1]
    // d_in[5] = ba: constant pre-softmax shift -> mathematically irrelevant.

    char* ws = (char*)d_ws;
    unsigned short* Wb  = (unsigned short*)(ws + OFF_WB);
    float*          P   = (float*)(ws + OFF_P);
    unsigned short* xT  = (unsigned short*)(ws + OFF_XT);
    unsigned short* a   = (unsigned short*)(ws + OFF_A);

    prep_xt<<<9 + ROWS_ / 4, 256, 0, stream>>>(Wt, Wx, x, Wb, xT);
    proj_q<<<128, 64, 0, stream>>>(x, Wb, bh, P);
    alpha_kernel<<<ROWS_ / 4, 256, 0, stream>>>(P, Wa, x, a);
    out_gemm_kernel<<<B_ * 32 * 16, 64, 0, stream>>>(a, xT, x, d_out);
}